// Round 16
// baseline (832.920 us; speedup 1.0000x reference)
//
#include <hip/hip_runtime.h>
#include <hip/hip_fp16.h>

// ---------------------------------------------------------------------------
// WQLinear_GEMM: out = x @ dequant(qweight,qzeros,scales) + bias
// detect -> fused prep (convert x || dequant Wt) -> GEMM.
// Round 16: r13's schedule (best: 3-slot ring, distance-2 prefetch, ONE
// barrier + counted vmcnt per BK=32 step, front-loaded reads, setprio,
// chunk-XOR swizzle) on a 256x128 tile sized for 2 BLOCKS/CU:
//   - 8 waves as 4M x 2N, 64x64/wave -> acc[4][4] = 64 regs; total ~118
//     fits __launch_bounds__(512,4)'s 128-reg cap WITHOUT spill (r10's
//     failure was acc[8][4]=128 under the same cap).
//   - LDS: 3 slots x 24KB = 72KB -> 2 blocks/CU (144KB <= 160KB).
//   - 2 co-resident blocks mask each other's barrier/vmcnt stalls (m114) --
//     the one axis never validly tested (every 256^2 variant was 1 block/CU,
//     Occupancy ~20%).
//   - 3 gload units/step (A 2 + B 1), ring ledger: VMC3 drains T+1's loads,
//     leaves T+2's 3 in flight. Hazard proof identical to r13/r9.
// grid = (8192/256)*(11008/128) = 32*86 = 2752; 8|2752 -> bijective XCD
// swizzle; consecutive swz share tm -> same A panel in XCD L2.
// ---------------------------------------------------------------------------

#define K_DIM 4096
#define N_DIM 11008
#define M_DIM 8192
#define NPACK 1376   // N_DIM/8

typedef __attribute__((ext_vector_type(8))) short short8;
typedef __attribute__((ext_vector_type(4))) short short4v;
typedef __attribute__((ext_vector_type(4))) float f32x4;

__device__ __forceinline__ unsigned short f32_to_bf16(float f) {
    union { float f; unsigned int u; } v; v.f = f;
    unsigned int u = v.u;
    unsigned int r = (u + 0x7FFFu + ((u >> 16) & 1u)) >> 16;  // RNE
    return (unsigned short)r;
}
__device__ __forceinline__ float bf16_to_f32(unsigned short u) {
    union { float f; unsigned int i; } v; v.i = (unsigned int)u << 16;
    return v.f;
}
// t: 0 = f16, 1 = bf16, 2 = f32
__device__ __forceinline__ float load16(const void* p, long idx, int t) {
    if (t == 1) return bf16_to_f32(((const unsigned short*)p)[idx]);
    if (t == 2) return ((const float*)p)[idx];
    return __half2float(((const __half*)p)[idx]);
}

// ---------------- kernel 0: dtype detection ----------------
__global__ void detect_kernel(const void* __restrict__ sc,
                              const void* __restrict__ bi,
                              const void* __restrict__ x,
                              int* __restrict__ flags) {
    __shared__ int cnt[8];
    const int tid = threadIdx.x;
    if (tid < 8) cnt[tid] = 0;
    __syncthreads();
    int l[8] = {0,0,0,0,0,0,0,0};
#pragma unroll
    for (int j = 0; j < 8; ++j) {
        const int s = tid * 8 + j;            // 0..2047
        const int is = s * 86;
        { float v = __half2float(((const __half*)sc)[is]);      if (v > 1e-6f && v < 0.0101f) l[0]++; }
        { float v = bf16_to_f32(((const unsigned short*)sc)[is]); if (v > 1e-6f && v < 0.0101f) l[1]++; }
        { float v = ((const float*)sc)[is];                     if (v > 1e-6f && v < 0.0101f) l[2]++; }
        const int ib = s * 2 + 1;
        { float v = fabsf(__half2float(((const __half*)bi)[ib]));      if (v > 1e-5f && v < 0.08f) l[3]++; }
        { float v = fabsf(bf16_to_f32(((const unsigned short*)bi)[ib])); if (v > 1e-5f && v < 0.08f) l[4]++; }
        { float v = fabsf(((const float*)bi)[ib]);                     if (v > 1e-5f && v < 0.08f) l[5]++; }
        const long xi = (long)s * 8191 + 7;
        { float v = fabsf(((const float*)x)[xi]);                      if (v > 1e-5f && v < 20.f) l[6]++; }
        { float v = fabsf(bf16_to_f32(((const unsigned short*)x)[xi])); if (v > 1e-5f && v < 20.f) l[7]++; }
    }
#pragma unroll
    for (int i = 0; i < 8; ++i) atomicAdd(&cnt[i], l[i]);
    __syncthreads();
    if (tid == 0) {
        int st = 0; if (cnt[1] > cnt[st]) st = 1; if (cnt[2] > cnt[st]) st = 2;
        int bt = 0; if (cnt[4] > cnt[3 + bt]) bt = 1; if (cnt[5] > cnt[3 + bt]) bt = 2;
        const int xt = (cnt[7] >= (2048 * 9) / 10) ? 1 : 0;
        flags[0] = st; flags[1] = bt; flags[2] = xt;
    }
}

// ---------------- kernel 1: fused prep (convert x || dequant Wt) ----------------
#define CONV_BLOCKS 2048
#define DEQ_BLOCKS  5504
__global__ void prep_kernel(const void* __restrict__ xr,
                            unsigned short* __restrict__ xb,
                            const int* __restrict__ qw,
                            const int* __restrict__ qz,
                            const void* __restrict__ sc,
                            unsigned short* __restrict__ wt,
                            const int* __restrict__ flags) {
    if (blockIdx.x < CONV_BLOCKS) {
        const int xt = flags[2];
        int i = blockIdx.x * blockDim.x + threadIdx.x;
        const int stride = CONV_BLOCKS * 256;
        const int n8 = (M_DIM * K_DIM) / 8;
        if (xt == 0) {
            const float4* xf = (const float4*)xr;
            for (; i < n8; i += stride) {
                float4 a = xf[2 * i], b = xf[2 * i + 1];
                short8 v;
                v[0] = (short)f32_to_bf16(a.x); v[1] = (short)f32_to_bf16(a.y);
                v[2] = (short)f32_to_bf16(a.z); v[3] = (short)f32_to_bf16(a.w);
                v[4] = (short)f32_to_bf16(b.x); v[5] = (short)f32_to_bf16(b.y);
                v[6] = (short)f32_to_bf16(b.z); v[7] = (short)f32_to_bf16(b.w);
                reinterpret_cast<short8*>(xb)[i] = v;
            }
        } else {
            const short8* xs = (const short8*)xr;
            for (; i < n8; i += stride)
                reinterpret_cast<short8*>(xb)[i] = xs[i];
        }
    } else {
        const int st = flags[0];
        const int order[8] = {0, 4, 1, 5, 2, 6, 3, 7};
        int tid = (blockIdx.x - CONV_BLOCKS) * blockDim.x + threadIdx.x;
        const int stride = DEQ_BLOCKS * 256;
        for (; tid < K_DIM * NPACK; tid += stride) {
            const int k = tid & (K_DIM - 1);
            const int c = tid >> 12;
            const int g = k >> 7;
            const int w = qw[k * NPACK + c];
            const int z = qz[g * NPACK + c];
#pragma unroll
            for (int j = 0; j < 8; ++j) {
                const int sh = order[j] * 4;
                const int iw = (w >> sh) & 15;
                const int iz = (z >> sh) & 15;
                const float s = load16(sc, (long)g * N_DIM + c * 8 + j, st);
                wt[(size_t)(c * 8 + j) * K_DIM + k] = f32_to_bf16((float)(iw - iz) * s);
            }
        }
    }
}

// ---------------- kernel 2: 256x128 GEMM, BK=32, 3-slot ring, 2 blk/CU ----------------
#define G_BM 256
#define G_BN 128
#define G_BK 32
#define NSTEP (K_DIM / G_BK)   // 128
#define SLOT  12288            // shorts per slot: A 8192 + B 4096 = 24KB

#define GLOAD(gptr, lptr) __builtin_amdgcn_global_load_lds( \
    (const __attribute__((address_space(1))) void*)(gptr),  \
    (__attribute__((address_space(3))) void*)(lptr), 16, 0, 0)

__global__ __launch_bounds__(512, 4) void gemm256_kernel(
    const unsigned short* __restrict__ A,   // xb [M][K]
    const unsigned short* __restrict__ B,   // Wt [N][K]
    const void* __restrict__ bias,
    const int* __restrict__ flags,
    float* __restrict__ C) {
    extern __shared__ unsigned short lds[];   // 3 slots x 24KB = 72KB

    const int bt = flags ? flags[1] : 0;

    const int tid  = threadIdx.x;
    const int lane = tid & 63;
    const int llo  = lane & 15;
    const int lhi  = lane >> 4;
    const int w    = tid >> 6;      // 0..7
    const int wr   = w >> 1;        // 0..3  (M quarter: 64 rows)
    const int wcn  = w & 1;         // 0..1  (N half: 64 cols)
    const int chsw = lhi ^ ((llo >> 1) & 3);   // conflict-free swizzled chunk

    // bijective XCD swizzle: 2752 = 8 * 344
    const int bid = blockIdx.x;
    const int swz = (bid & 7) * 344 + (bid >> 3);
    const int tm = swz / 86;        // 0..31
    const int tn = swz - tm * 86;   // 0..85
    const int row0 = tm * G_BM;
    const int col0 = tn * G_BN;

    // staging: thread -> (srow 0..127, schunk 0..3); source chunk pre-swizzled
    const int srow   = tid >> 2;
    const int schunk = tid & 3;
    const int cs     = schunk ^ ((srow >> 1) & 3);
    const unsigned short* Ab = A + (size_t)(row0 + srow) * K_DIM + cs * 8;
    const unsigned short* Bb = B + (size_t)(col0 + srow) * K_DIM + cs * 8;
    const size_t rstep = (size_t)128 * K_DIM;
    const int dofs = srow * 32 + schunk * 8;

// slot layout (shorts): A rows 0-127 @0, A rows 128-255 @4096, B @8192
#define STAGE(slot, kofs) do {                                                \
    GLOAD(Ab + (kofs),         lds + (slot) + dofs);                          \
    GLOAD(Ab + (kofs) + rstep, lds + (slot) + 4096 + dofs);                   \
    GLOAD(Bb + (kofs),         lds + (slot) + 8192 + dofs);                   \
  } while (0)

#define VMC3 asm volatile("s_waitcnt vmcnt(3)" ::: "memory")
#define BAR  __builtin_amdgcn_s_barrier()

    f32x4 acc[4][4] = {};
    short8 af[4], bf[4];

    // prologue: stage tiles 0 and 1
    STAGE(0, 0);
    STAGE(SLOT, G_BK);
    VMC3;    // tile 0 landed; tile 1 in flight
    BAR;

    int s_cur = 0, s_nxt = SLOT, s_pre = 2 * SLOT;

#pragma unroll 1
    for (int T = 0; T < NSTEP; ++T) {
        const int kofs = (T + 2 < NSTEP ? T + 2 : NSTEP - 1) * G_BK;

        // ---- front-load all 8 fragment reads ----
#pragma unroll
        for (int n = 0; n < 4; ++n) {
            const int r = wcn * 64 + n * 16 + llo;
            bf[n] = *reinterpret_cast<const short8*>(lds + s_cur + 8192 + r * 32 + chsw * 8);
        }
#pragma unroll
        for (int m = 0; m < 4; ++m) {
            const int r = wr * 64 + m * 16 + llo;
            af[m] = *reinterpret_cast<const short8*>(lds + s_cur + r * 32 + chsw * 8);
        }
        // ---- stage tile T+2 into s_pre ----
        STAGE(s_pre, kofs);

        // ---- 16-MFMA cluster ----
        __builtin_amdgcn_s_setprio(1);
#pragma unroll
        for (int m = 0; m < 4; ++m)
#pragma unroll
            for (int n = 0; n < 4; ++n)
                acc[m][n] = __builtin_amdgcn_mfma_f32_16x16x32_bf16(af[m], bf[n], acc[m][n], 0, 0, 0);
        __builtin_amdgcn_s_setprio(0);

        VMC3;    // lands tile T+1; tile T+2's 3 loads stay in flight
        BAR;     // slot[T+1] globally valid; all waves done reading slot[T]

        const int t = s_cur; s_cur = s_nxt; s_nxt = s_pre; s_pre = t;
    }

    // ---- epilogue: C = acc + bias (nontemporal stores) ----
#pragma unroll
    for (int n = 0; n < 4; ++n) {
        const int col = col0 + wcn * 64 + n * 16 + llo;
        const float bi = load16(bias, col, bt);
#pragma unroll
        for (int m = 0; m < 4; ++m) {
            const int row = row0 + wr * 64 + m * 16 + lhi * 4;
#pragma unroll
            for (int i = 0; i < 4; ++i)
                __builtin_nontemporal_store(acc[m][n][i] + bi,
                                            &C[(size_t)(row + i) * N_DIM + col]);
        }
    }
#undef STAGE
#undef VMC3
#undef BAR
}

// ---------------- fallback: fully-fused 128x128 (small ws) ----------------
#define BM 128
#define BN 128
#define BK 64
#define LDK 72

__global__ __launch_bounds__(256) void gemm_fused_kernel(
    const float* __restrict__ Af32,
    const int* __restrict__ qw,
    const int* __restrict__ qz,
    const void* __restrict__ sc,
    const void* __restrict__ bias,
    float* __restrict__ C) {
    __shared__ unsigned short As[BM][LDK];
    __shared__ unsigned short Bs[BN][LDK];
    const int tid  = threadIdx.x;
    const int lane = tid & 63;
    const int lhi  = lane >> 4;
    const int llo  = lane & 15;
    const int wv   = tid >> 6;
    const int wr   = wv >> 1;
    const int wc   = wv & 1;
    const int row0 = blockIdx.y * BM;
    const int col0 = blockIdx.x * BN;
    const int lrow = tid >> 3;
    const int lcol = (tid & 7) * 8;
    f32x4 acc[4][4] = {};
    for (int kt = 0; kt < K_DIM; kt += BK) {
#pragma unroll
        for (int r = 0; r < 4; ++r) {
            const float* p = Af32 + (size_t)(row0 + r * 32 + lrow) * K_DIM + kt + lcol;
            float4 x0 = *reinterpret_cast<const float4*>(p);
            float4 x1 = *reinterpret_cast<const float4*>(p + 4);
            short8 v;
            v[0] = (short)f32_to_bf16(x0.x); v[1] = (short)f32_to_bf16(x0.y);
            v[2] = (short)f32_to_bf16(x0.z); v[3] = (short)f32_to_bf16(x0.w);
            v[4] = (short)f32_to_bf16(x1.x); v[5] = (short)f32_to_bf16(x1.y);
            v[6] = (short)f32_to_bf16(x1.z); v[7] = (short)f32_to_bf16(x1.w);
            *reinterpret_cast<short8*>(&As[r * 32 + lrow][lcol]) = v;
        }
        {
            const int pc  = tid & 15;
            const int kq  = tid >> 4;
            const int g   = kt >> 7;
            const int pcg = (col0 >> 3) + pc;
            const int z   = qz[g * NPACK + pcg];
            int wv4[4];
#pragma unroll
            for (int q = 0; q < 4; ++q)
                wv4[q] = qw[(size_t)(kt + kq * 4 + q) * NPACK + pcg];
            const int order[8] = {0, 4, 1, 5, 2, 6, 3, 7};
#pragma unroll
            for (int j = 0; j < 8; ++j) {
                const int sh = order[j] * 4;
                const int zj = (z >> sh) & 15;
                const float sj = __half2float(((const __half*)sc)[(long)g * N_DIM + col0 + pc * 8 + j]);
                short4v o;
#pragma unroll
                for (int q = 0; q < 4; ++q) {
                    const int iw = (wv4[q] >> sh) & 15;
                    o[q] = (short)f32_to_bf16((float)(iw - zj) * sj);
                }
                *reinterpret_cast<short4v*>(&Bs[pc * 8 + j][kq * 4]) = o;
            }
        }
        __syncthreads();
#pragma unroll
        for (int kk = 0; kk < 2; ++kk) {
            const int ko = kk * 32 + lhi * 8;
            short8 af[4], bf[4];
#pragma unroll
            for (int m = 0; m < 4; ++m)
                af[m] = *reinterpret_cast<const short8*>(&As[wr * 64 + m * 16 + llo][ko]);
#pragma unroll
            for (int n = 0; n < 4; ++n)
                bf[n] = *reinterpret_cast<const short8*>(&Bs[wc * 64 + n * 16 + llo][ko]);
#pragma unroll
            for (int m = 0; m < 4; ++m)
#pragma unroll
                for (int n = 0; n < 4; ++n)
                    acc[m][n] = __builtin_amdgcn_mfma_f32_16x16x32_bf16(af[m], bf[n], acc[m][n], 0, 0, 0);
        }
        __syncthreads();
    }
#pragma unroll
    for (int n = 0; n < 4; ++n) {
        const int col = col0 + wc * 64 + n * 16 + llo;
        const float bi = __half2float(((const __half*)bias)[col]);
#pragma unroll
        for (int m = 0; m < 4; ++m) {
            const int row = row0 + wr * 64 + m * 16 + lhi * 4;
#pragma unroll
            for (int i = 0; i < 4; ++i)
                C[(size_t)(row + i) * N_DIM + col] = acc[m][n][i] + bi;
        }
    }
}

static const void* ptr_by_size(void* const* d_in, const int* in_sizes, int n_in,
                               long want, int def_idx) {
    for (int i = 0; i < n_in; ++i)
        if ((long)in_sizes[i] == want) return d_in[i];
    return d_in[def_idx];
}

extern "C" void kernel_launch(void* const* d_in, const int* in_sizes, int n_in,
                              void* d_out, int out_size, void* d_ws, size_t ws_size,
                              hipStream_t stream) {
    const void* x    = ptr_by_size(d_in, in_sizes, n_in, (long)M_DIM * K_DIM, 0);
    const int*  qw   = (const int*)ptr_by_size(d_in, in_sizes, n_in, (long)K_DIM * NPACK, 1);
    const int*  qz   = (const int*)ptr_by_size(d_in, in_sizes, n_in, (long)(K_DIM / 128) * NPACK, 2);
    const void* sc   = ptr_by_size(d_in, in_sizes, n_in, (long)(K_DIM / 128) * N_DIM, 3);
    const void* bias = ptr_by_size(d_in, in_sizes, n_in, (long)N_DIM, 4);
    float*      out  = (float*)d_out;

    const size_t xb_bytes = (size_t)M_DIM * K_DIM * 2;   // 67.1 MB
    const size_t wt_bytes = (size_t)N_DIM * K_DIM * 2;   // 90.2 MB
    unsigned short* xb = (unsigned short*)d_ws;
    unsigned short* wt = (unsigned short*)((char*)d_ws + xb_bytes);

    int* flags = nullptr;
    if (ws_size >= 32)
        flags = (int*)(((uintptr_t)d_ws + ws_size - 16) & ~(uintptr_t)15);

    if (flags && ws_size >= xb_bytes + wt_bytes + 32) {
        detect_kernel<<<1, 256, 0, stream>>>(sc, bias, x, flags);
        prep_kernel<<<CONV_BLOCKS + DEQ_BLOCKS, 256, 0, stream>>>(
            x, xb, qw, qz, sc, wt, flags);
        hipFuncSetAttribute(reinterpret_cast<const void*>(gemm256_kernel),
                            hipFuncAttributeMaxDynamicSharedMemorySize, 73728);
        gemm256_kernel<<<(M_DIM / G_BM) * (N_DIM / G_BN), 512, 73728, stream>>>(
            xb, wt, bias, flags, out);
    } else {
        dim3 grid(N_DIM / BN, M_DIM / BM);
        gemm_fused_kernel<<<grid, 256, 0, stream>>>(
            (const float*)x, qw, qz, sc, bias, out);
    }
}

// Round 17
// 788.297 us; speedup vs baseline: 1.0566x; 1.0566x over previous
//
#include <hip/hip_runtime.h>
#include <hip/hip_fp16.h>

// ---------------------------------------------------------------------------
// WQLinear_GEMM: out = x @ dequant(qweight,qzeros,scales) + bias
// detect dtypes -> prep (convert x + dequant Wt fused, one dispatch) -> GEMM.
// FINAL (= round 13, measured best 795.9us total / ~718us GEMM = 1.03 PF):
// GEMM core: 256x256 tile, BK=32, 3-slot LDS ring (96KB), distance-2
// prefetch, vmcnt(4) once/step never 0, ONE barrier/step, no manual lgkm
// fences (compiler emits fine-grained lgkmcnt), front-loaded 12 b128
// fragment reads before one 32-MFMA cluster, setprio around MFMA,
// chunk-XOR swizzle (SQ_LDS_BANK_CONFLICT=0), bijective XCD swizzle,
// nontemporal C stores. Campaign notes (r5-r16): sync topology 2/4/8 per
// K-tile -> 4 (this) is optimal; 32x32 MFMA, B-in-registers, fragment-major
// packing, 2 blocks/CU occupancy all null or regressions. Remaining gap to
// dense peak is structural: barrier-locked LDS<->MFMA serialization plus
// ~10% grid-tail (1376 blocks = 5.375 CU-rounds, 43 prime).
// ---------------------------------------------------------------------------

#define K_DIM 4096
#define N_DIM 11008
#define M_DIM 8192
#define NPACK 1376   // N_DIM/8

typedef __attribute__((ext_vector_type(8))) short short8;
typedef __attribute__((ext_vector_type(4))) short short4v;
typedef __attribute__((ext_vector_type(4))) float f32x4;

__device__ __forceinline__ unsigned short f32_to_bf16(float f) {
    union { float f; unsigned int u; } v; v.f = f;
    unsigned int u = v.u;
    unsigned int r = (u + 0x7FFFu + ((u >> 16) & 1u)) >> 16;  // RNE
    return (unsigned short)r;
}
__device__ __forceinline__ float bf16_to_f32(unsigned short u) {
    union { float f; unsigned int i; } v; v.i = (unsigned int)u << 16;
    return v.f;
}
// t: 0 = f16, 1 = bf16, 2 = f32
__device__ __forceinline__ float load16(const void* p, long idx, int t) {
    if (t == 1) return bf16_to_f32(((const unsigned short*)p)[idx]);
    if (t == 2) return ((const float*)p)[idx];
    return __half2float(((const __half*)p)[idx]);
}

// ---------------- kernel 0: dtype detection ----------------
__global__ void detect_kernel(const void* __restrict__ sc,
                              const void* __restrict__ bi,
                              const void* __restrict__ x,
                              int* __restrict__ flags) {
    __shared__ int cnt[8];
    const int tid = threadIdx.x;
    if (tid < 8) cnt[tid] = 0;
    __syncthreads();
    int l[8] = {0,0,0,0,0,0,0,0};
#pragma unroll
    for (int j = 0; j < 8; ++j) {
        const int s = tid * 8 + j;            // 0..2047
        const int is = s * 86;
        { float v = __half2float(((const __half*)sc)[is]);      if (v > 1e-6f && v < 0.0101f) l[0]++; }
        { float v = bf16_to_f32(((const unsigned short*)sc)[is]); if (v > 1e-6f && v < 0.0101f) l[1]++; }
        { float v = ((const float*)sc)[is];                     if (v > 1e-6f && v < 0.0101f) l[2]++; }
        const int ib = s * 2 + 1;
        { float v = fabsf(__half2float(((const __half*)bi)[ib]));      if (v > 1e-5f && v < 0.08f) l[3]++; }
        { float v = fabsf(bf16_to_f32(((const unsigned short*)bi)[ib])); if (v > 1e-5f && v < 0.08f) l[4]++; }
        { float v = fabsf(((const float*)bi)[ib]);                     if (v > 1e-5f && v < 0.08f) l[5]++; }
        const long xi = (long)s * 8191 + 7;
        { float v = fabsf(((const float*)x)[xi]);                      if (v > 1e-5f && v < 20.f) l[6]++; }
        { float v = fabsf(bf16_to_f32(((const unsigned short*)x)[xi])); if (v > 1e-5f && v < 20.f) l[7]++; }
    }
#pragma unroll
    for (int i = 0; i < 8; ++i) atomicAdd(&cnt[i], l[i]);
    __syncthreads();
    if (tid == 0) {
        int st = 0; if (cnt[1] > cnt[st]) st = 1; if (cnt[2] > cnt[st]) st = 2;
        int bt = 0; if (cnt[4] > cnt[3 + bt]) bt = 1; if (cnt[5] > cnt[3 + bt]) bt = 2;
        const int xt = (cnt[7] >= (2048 * 9) / 10) ? 1 : 0;
        flags[0] = st; flags[1] = bt; flags[2] = xt;
    }
}

// ---------------- kernel 1: fused prep (convert x || dequant Wt) ----------------
#define CONV_BLOCKS 2048
#define DEQ_BLOCKS  5504
__global__ void prep_kernel(const void* __restrict__ xr,
                            unsigned short* __restrict__ xb,
                            const int* __restrict__ qw,
                            const int* __restrict__ qz,
                            const void* __restrict__ sc,
                            unsigned short* __restrict__ wt,
                            const int* __restrict__ flags) {
    if (blockIdx.x < CONV_BLOCKS) {
        // ---- convert x -> bf16 ----
        const int xt = flags[2];
        int i = blockIdx.x * blockDim.x + threadIdx.x;
        const int stride = CONV_BLOCKS * 256;
        const int n8 = (M_DIM * K_DIM) / 8;
        if (xt == 0) {
            const float4* xf = (const float4*)xr;
            for (; i < n8; i += stride) {
                float4 a = xf[2 * i], b = xf[2 * i + 1];
                short8 v;
                v[0] = (short)f32_to_bf16(a.x); v[1] = (short)f32_to_bf16(a.y);
                v[2] = (short)f32_to_bf16(a.z); v[3] = (short)f32_to_bf16(a.w);
                v[4] = (short)f32_to_bf16(b.x); v[5] = (short)f32_to_bf16(b.y);
                v[6] = (short)f32_to_bf16(b.z); v[7] = (short)f32_to_bf16(b.w);
                reinterpret_cast<short8*>(xb)[i] = v;
            }
        } else {
            const short8* xs = (const short8*)xr;
            for (; i < n8; i += stride)
                reinterpret_cast<short8*>(xb)[i] = xs[i];
        }
    } else {
        // ---- dequant -> Wt[N][K] bf16 ----
        const int st = flags[0];
        const int order[8] = {0, 4, 1, 5, 2, 6, 3, 7};
        int tid = (blockIdx.x - CONV_BLOCKS) * blockDim.x + threadIdx.x;
        const int stride = DEQ_BLOCKS * 256;
        for (; tid < K_DIM * NPACK; tid += stride) {
            const int k = tid & (K_DIM - 1);
            const int c = tid >> 12;
            const int g = k >> 7;
            const int w = qw[k * NPACK + c];
            const int z = qz[g * NPACK + c];
#pragma unroll
            for (int j = 0; j < 8; ++j) {
                const int sh = order[j] * 4;
                const int iw = (w >> sh) & 15;
                const int iz = (z >> sh) & 15;
                const float s = load16(sc, (long)g * N_DIM + c * 8 + j, st);
                wt[(size_t)(c * 8 + j) * K_DIM + k] = f32_to_bf16((float)(iw - iz) * s);
            }
        }
    }
}

// ---------------- kernel 2: 256x256 GEMM, BK=32, 3-slot ring ----------------
#define G_BM 256
#define G_BN 256
#define G_BK 32
#define NSTEP (K_DIM / G_BK)   // 128
#define SLOT  16384            // shorts per ring slot (A 8192 + B 8192 = 32KB)

#define GLOAD(gptr, lptr) __builtin_amdgcn_global_load_lds( \
    (const __attribute__((address_space(1))) void*)(gptr),  \
    (__attribute__((address_space(3))) void*)(lptr), 16, 0, 0)

__global__ __launch_bounds__(512, 2) void gemm256_kernel(
    const unsigned short* __restrict__ A,   // xb [M][K]
    const unsigned short* __restrict__ B,   // Wt [N][K]
    const void* __restrict__ bias,
    const int* __restrict__ flags,
    float* __restrict__ C) {
    extern __shared__ unsigned short lds[];   // 3 slots x 32KB = 96KB

    const int bt = flags ? flags[1] : 0;

    const int tid  = threadIdx.x;
    const int lane = tid & 63;
    const int llo  = lane & 15;
    const int lhi  = lane >> 4;
    const int w    = tid >> 6;      // 0..7
    const int wr   = w >> 2;        // 0..1  (M half)
    const int wcn  = w & 3;         // 0..3  (N quarter)
    const int chsw = lhi ^ ((llo >> 1) & 3);   // conflict-free swizzled chunk

    // bijective XCD swizzle: 1376 = 8 * 172
    const int bid = blockIdx.x;
    const int swz = (bid & 7) * 172 + (bid >> 3);
    const int tm = swz / 43;
    const int tn = swz - tm * 43;
    const int row0 = tm * G_BM;
    const int col0 = tn * G_BN;

    // staging: thread -> (srow, schunk); 4 chunks of 8 bf16 per 32-k row
    const int srow   = tid >> 2;                   // 0..127
    const int schunk = tid & 3;                    // 0..3
    const int cs     = schunk ^ ((srow >> 1) & 3); // pre-swizzled source chunk
    const unsigned short* Ab = A + (size_t)(row0 + srow) * K_DIM + cs * 8;
    const unsigned short* Bb = B + (size_t)(col0 + srow) * K_DIM + cs * 8;
    const size_t rstep = (size_t)128 * K_DIM;
    const int dofs = srow * 32 + schunk * 8;       // lds dest offset (shorts)

#define STAGE(slot, kofs) do {                                                \
    GLOAD(Ab + (kofs),         lds + (slot) + dofs);                          \
    GLOAD(Ab + (kofs) + rstep, lds + (slot) + 4096 + dofs);                   \
    GLOAD(Bb + (kofs),         lds + (slot) + 8192 + dofs);                   \
    GLOAD(Bb + (kofs) + rstep, lds + (slot) + 12288 + dofs);                  \
  } while (0)

#define VMC4 asm volatile("s_waitcnt vmcnt(4)" ::: "memory")
#define BAR  __builtin_amdgcn_s_barrier()

    f32x4 acc[8][4] = {};
    short8 af[8], bf[4];

    // prologue: stage tiles 0 and 1
    STAGE(0, 0);
    STAGE(SLOT, G_BK);
    VMC4;    // tile 0 landed; tile 1 in flight
    BAR;

    int s_cur = 0, s_nxt = SLOT, s_pre = 2 * SLOT;

#pragma unroll 1
    for (int T = 0; T < NSTEP; ++T) {
        const int kofs = (T + 2 < NSTEP ? T + 2 : NSTEP - 1) * G_BK;

        // ---- front-load ALL fragment reads (12 x b128) ----
#pragma unroll
        for (int n = 0; n < 4; ++n) {
            const int r = wcn * 64 + n * 16 + llo;
            bf[n] = *reinterpret_cast<const short8*>(lds + s_cur + 8192 + r * 32 + chsw * 8);
        }
#pragma unroll
        for (int m = 0; m < 8; ++m) {
            const int r = wr * 128 + m * 16 + llo;
            af[m] = *reinterpret_cast<const short8*>(lds + s_cur + r * 32 + chsw * 8);
        }
        // ---- stage tile T+2 into s_pre ----
        STAGE(s_pre, kofs);

        // ---- single 32-MFMA cluster (compiler interleaves lgkm waits) ----
        __builtin_amdgcn_s_setprio(1);
#pragma unroll
        for (int m = 0; m < 8; ++m)
#pragma unroll
            for (int n = 0; n < 4; ++n)
                acc[m][n] = __builtin_amdgcn_mfma_f32_16x16x32_bf16(af[m], bf[n], acc[m][n], 0, 0, 0);
        __builtin_amdgcn_s_setprio(0);

        VMC4;    // lands tile T+1; tile T+2 stays in flight
        BAR;     // slot[T+1] globally valid; all waves done reading slot[T]

        const int t = s_cur; s_cur = s_nxt; s_nxt = s_pre; s_pre = t;
    }

    // ---- epilogue: C = acc + bias (nontemporal stores) ----
#pragma unroll
    for (int n = 0; n < 4; ++n) {
        const int col = col0 + wcn * 64 + n * 16 + llo;
        const float bi = load16(bias, col, bt);
#pragma unroll
        for (int m = 0; m < 8; ++m) {
            const int row = row0 + wr * 128 + m * 16 + lhi * 4;
#pragma unroll
            for (int i = 0; i < 4; ++i)
                __builtin_nontemporal_store(acc[m][n][i] + bi,
                                            &C[(size_t)(row + i) * N_DIM + col]);
        }
    }
#undef STAGE
#undef VMC4
#undef BAR
}

// ---------------- fallback: fully-fused 128x128 (small ws) ----------------
#define BM 128
#define BN 128
#define BK 64
#define LDK 72

__global__ __launch_bounds__(256) void gemm_fused_kernel(
    const float* __restrict__ Af32,
    const int* __restrict__ qw,
    const int* __restrict__ qz,
    const void* __restrict__ sc,
    const void* __restrict__ bias,
    float* __restrict__ C) {
    __shared__ unsigned short As[BM][LDK];
    __shared__ unsigned short Bs[BN][LDK];
    const int tid  = threadIdx.x;
    const int lane = tid & 63;
    const int lhi  = lane >> 4;
    const int llo  = lane & 15;
    const int wv   = tid >> 6;
    const int wr   = wv >> 1;
    const int wc   = wv & 1;
    const int row0 = blockIdx.y * BM;
    const int col0 = blockIdx.x * BN;
    const int lrow = tid >> 3;
    const int lcol = (tid & 7) * 8;
    f32x4 acc[4][4] = {};
    for (int kt = 0; kt < K_DIM; kt += BK) {
#pragma unroll
        for (int r = 0; r < 4; ++r) {
            const float* p = Af32 + (size_t)(row0 + r * 32 + lrow) * K_DIM + kt + lcol;
            float4 x0 = *reinterpret_cast<const float4*>(p);
            float4 x1 = *reinterpret_cast<const float4*>(p + 4);
            short8 v;
            v[0] = (short)f32_to_bf16(x0.x); v[1] = (short)f32_to_bf16(x0.y);
            v[2] = (short)f32_to_bf16(x0.z); v[3] = (short)f32_to_bf16(x0.w);
            v[4] = (short)f32_to_bf16(x1.x); v[5] = (short)f32_to_bf16(x1.y);
            v[6] = (short)f32_to_bf16(x1.z); v[7] = (short)f32_to_bf16(x1.w);
            *reinterpret_cast<short8*>(&As[r * 32 + lrow][lcol]) = v;
        }
        {
            const int pc  = tid & 15;
            const int kq  = tid >> 4;
            const int g   = kt >> 7;
            const int pcg = (col0 >> 3) + pc;
            const int z   = qz[g * NPACK + pcg];
            int wv4[4];
#pragma unroll
            for (int q = 0; q < 4; ++q)
                wv4[q] = qw[(size_t)(kt + kq * 4 + q) * NPACK + pcg];
            const int order[8] = {0, 4, 1, 5, 2, 6, 3, 7};
#pragma unroll
            for (int j = 0; j < 8; ++j) {
                const int sh = order[j] * 4;
                const int zj = (z >> sh) & 15;
                const float sj = __half2float(((const __half*)sc)[(long)g * N_DIM + col0 + pc * 8 + j]);
                short4v o;
#pragma unroll
                for (int q = 0; q < 4; ++q) {
                    const int iw = (wv4[q] >> sh) & 15;
                    o[q] = (short)f32_to_bf16((float)(iw - zj) * sj);
                }
                *reinterpret_cast<short4v*>(&Bs[pc * 8 + j][kq * 4]) = o;
            }
        }
        __syncthreads();
#pragma unroll
        for (int kk = 0; kk < 2; ++kk) {
            const int ko = kk * 32 + lhi * 8;
            short8 af[4], bf[4];
#pragma unroll
            for (int m = 0; m < 4; ++m)
                af[m] = *reinterpret_cast<const short8*>(&As[wr * 64 + m * 16 + llo][ko]);
#pragma unroll
            for (int n = 0; n < 4; ++n)
                bf[n] = *reinterpret_cast<const short8*>(&Bs[wc * 64 + n * 16 + llo][ko]);
#pragma unroll
            for (int m = 0; m < 4; ++m)
#pragma unroll
                for (int n = 0; n < 4; ++n)
                    acc[m][n] = __builtin_amdgcn_mfma_f32_16x16x32_bf16(af[m], bf[n], acc[m][n], 0, 0, 0);
        }
        __syncthreads();
    }
#pragma unroll
    for (int n = 0; n < 4; ++n) {
        const int col = col0 + wc * 64 + n * 16 + llo;
        const float bi = __half2float(((const __half*)bias)[col]);
#pragma unroll
        for (int m = 0; m < 4; ++m) {
            const int row = row0 + wr * 64 + m * 16 + lhi * 4;
#pragma unroll
            for (int i = 0; i < 4; ++i)
                C[(size_t)(row + i) * N_DIM + col] = acc[m][n][i] + bi;
        }
    }
}

static const void* ptr_by_size(void* const* d_in, const int* in_sizes, int n_in,
                               long want, int def_idx) {
    for (int i = 0; i < n_in; ++i)
        if ((long)in_sizes[i] == want) return d_in[i];
    return d_in[def_idx];
}

extern "C" void kernel_launch(void* const* d_in, const int* in_sizes, int n_in,
                              void* d_out, int out_size, void* d_ws, size_t ws_size,
                              hipStream_t stream) {
    const void* x    = ptr_by_size(d_in, in_sizes, n_in, (long)M_DIM * K_DIM, 0);
    const int*  qw   = (const int*)ptr_by_size(d_in, in_sizes, n_in, (long)K_DIM * NPACK, 1);
    const int*  qz   = (const int*)ptr_by_size(d_in, in_sizes, n_in, (long)(K_DIM / 128) * NPACK, 2);
    const void* sc   = ptr_by_size(d_in, in_sizes, n_in, (long)(K_DIM / 128) * N_DIM, 3);
    const void* bias = ptr_by_size(d_in, in_sizes, n_in, (long)N_DIM, 4);
    float*      out  = (float*)d_out;

    const size_t xb_bytes = (size_t)M_DIM * K_DIM * 2;   // 67.1 MB
    const size_t wt_bytes = (size_t)N_DIM * K_DIM * 2;   // 90.2 MB
    unsigned short* xb = (unsigned short*)d_ws;
    unsigned short* wt = (unsigned short*)((char*)d_ws + xb_bytes);

    int* flags = nullptr;
    if (ws_size >= 32)
        flags = (int*)(((uintptr_t)d_ws + ws_size - 16) & ~(uintptr_t)15);

    if (flags && ws_size >= xb_bytes + wt_bytes + 32) {
        detect_kernel<<<1, 256, 0, stream>>>(sc, bias, x, flags);
        prep_kernel<<<CONV_BLOCKS + DEQ_BLOCKS, 256, 0, stream>>>(
            x, xb, qw, qz, sc, wt, flags);
        hipFuncSetAttribute(reinterpret_cast<const void*>(gemm256_kernel),
                            hipFuncAttributeMaxDynamicSharedMemorySize, 98304);
        gemm256_kernel<<<(M_DIM / G_BM) * (N_DIM / G_BN), 512, 98304, stream>>>(
            xb, wt, bias, flags, out);
    } else {
        dim3 grid(N_DIM / BN, M_DIM / BM);
        gemm_fused_kernel<<<grid, 256, 0, stream>>>(
            (const float*)x, qw, qz, sc, bias, out);
    }
}